// Round 10
// baseline (208.593 us; speedup 1.0000x reference)
//
#include <hip/hip_runtime.h>
#include <math.h>

#define T_NTIME  2048
#define T_NBATCH 128
#define T_INSIZE 512
#define T_SIZE   16
#define T_NROWS  (T_NTIME * T_NBATCH)
#define MAT_STRIDE 24

typedef __attribute__((ext_vector_type(8))) short s8v;    // 8 bf16 (4 VGPR)
typedef __attribute__((ext_vector_type(4))) float f32x4;  // MFMA acc

__device__ __forceinline__ float sp_f(float v) {
  return fmaxf(v, 0.0f) + log1pf(__expf(-fabsf(v)));
}
__device__ __forceinline__ float tanh5_f(float v) {
  float a = fabsf(v);
  float e = __expf(-2.0f * a);
  float t = (1.0f - e) / (1.0f + e);
  return copysignf(5.0f * t, v);
}
__device__ __forceinline__ float lae_f(float a, float c) {
  float m = fmaxf(a, c);
  return m + log1pf(__expf(-fabsf(a - c)));
}
// RNE f32->bf16 + residual (used once for W pack)
__device__ __forceinline__ unsigned packw(float f) {
  unsigned u = __float_as_uint(f);
  unsigned hb = (u + 0x7fffu + ((u >> 16) & 1u)) >> 16;
  float hf = __uint_as_float(hb << 16);
  float l = f - hf;
  unsigned ul = __float_as_uint(l);
  unsigned lb = (ul + 0x7fffu + ((ul >> 16) & 1u)) >> 16;
  return (hb << 16) | (lb & 0xffffu);
}
// async global->LDS, 16B per lane, LDS dest = wave-uniform base + lane*16
__device__ __forceinline__ void gl_lds16(const float* g, float* lds) {
  __builtin_amdgcn_global_load_lds(
      (const __attribute__((address_space(1))) void*)g,
      (__attribute__((address_space(3))) void*)lds, 16, 0, 0);
}

// ---------- K1: wave-autonomous MFMA GEMM with global_load_lds staging ----------
// Wave owns 128 rows (8 tiles x 8 K-steps of 64). x staged via 4x
// global_load_lds(16B) per step into wave-private dbuf LDS; swizzle applied to
// the per-lane GLOBAL source address (16B-granule XOR within 128B lines ->
// coalescing kept, LDS dest linear). Counted s_waitcnt vmcnt(4) per step.
// W cached once in LDS as (bf16hi<<16)|bf16lo, swizzled. 3-chain hi/lo MFMA.
__global__ __launch_bounds__(256, 2)
void k1_gld(const float* __restrict__ x, const float* __restrict__ W,
            const float* __restrict__ bias, float* __restrict__ out) {
  __shared__ unsigned wp[16][512];       // 32 KB: slot g^(row&7), g = k/4
  __shared__ float xb[4][2][16][64];     // 32 KB: per-wave dbuf, slot gd^(row&7)
  const int tid = threadIdx.x;

  // one-time W pack (coalesced read, swizzled LDS write)
  {
    const float4* src = (const float4*)W;
#pragma unroll
    for (int k = 0; k < 8; ++k) {
      const int f4 = tid + k * 256;
      const float4 v = src[f4];
      const int s = f4 >> 7;
      const int g = f4 & 127;
      const int slot = g ^ (s & 7);
      uint4 p;
      p.x = packw(v.x); p.y = packw(v.y); p.z = packw(v.z); p.w = packw(v.w);
      *(uint4*)&wp[s][slot * 4] = p;
    }
  }
  __syncthreads();

  const int l = tid & 63;
  const int w = tid >> 6;
  const int lr = l & 15;        // fragment row (x-row within tile / W row)
  const int lk = (l >> 4) & 3;  // k-subgroup
  const int r7 = lr & 7;

  const long gw = (long)blockIdx.x * 4 + w;
  const long rowbase = gw * 128;
  float* xw = &xb[w][0][0][0];           // [2][16][64]
  const float4 bv = *(const float4*)(bias + lk * 4);

  // per-lane swizzled global source base for chunk c (c=0..3):
  // row-in-step r = 4c + (l>>4); slot = l&15; data granule gd = slot ^ (r&7)
  const float* gsrc[4];
#pragma unroll
  for (int c = 0; c < 4; ++c) {
    const int r = c * 4 + (l >> 4);
    const int gd = (l & 15) ^ (r & 7);
    gsrc[c] = x + (rowbase + r) * T_INSIZE + gd * 4;
  }

  // prologue: stage step 0 into buf 0
#pragma unroll
  for (int c = 0; c < 4; ++c) gl_lds16(gsrc[c], xw + c * 256);

  f32x4 acc = {0.f, 0.f, 0.f, 0.f};
#pragma unroll 1
  for (int m = 0; m < 64; ++m) {       // tile = m>>3, ks = m&7
    const int ks = m & 7;
    if (m < 63) {
      const int mn = m + 1;
      const long goff = (long)(mn >> 3) * (16 * T_INSIZE) + (long)(mn & 7) * 64;
      float* ldst = xw + (mn & 1) * 1024;
#pragma unroll
      for (int c = 0; c < 4; ++c) gl_lds16(gsrc[c] + goff, ldst + c * 256);
      asm volatile("s_waitcnt vmcnt(4)" ::: "memory");
    } else {
      asm volatile("s_waitcnt vmcnt(0)" ::: "memory");
    }

    const float* bufr = xw + (m & 1) * 1024;
#pragma unroll
    for (int chain = 0; chain < 2; ++chain) {
      // W fragment (packed hi/lo)
      const int gA = (ks << 4) + (chain << 3) + (lk << 1);
      const uint4 ua = *(const uint4*)&wp[lr][(gA ^ r7) * 4];
      const uint4 ub = *(const uint4*)&wp[lr][((gA + 1) ^ r7) * 4];
      union { uint4 u; s8v v; } AH, AL;
      AH.u.x = (ua.x >> 16) | (ua.y & 0xffff0000u);
      AL.u.x = (ua.x & 0xffffu) | (ua.y << 16);
      AH.u.y = (ua.z >> 16) | (ua.w & 0xffff0000u);
      AL.u.y = (ua.z & 0xffffu) | (ua.w << 16);
      AH.u.z = (ub.x >> 16) | (ub.y & 0xffff0000u);
      AL.u.z = (ub.x & 0xffffu) | (ub.y << 16);
      AH.u.w = (ub.z >> 16) | (ub.w & 0xffff0000u);
      AL.u.w = (ub.z & 0xffffu) | (ub.w << 16);

      // x fragment: truncation split, pair-packed
      const int gB = (chain << 3) + (lk << 1);
      const int s0 = gB ^ r7;
      const float4 b0 = *(const float4*)&bufr[lr * 64 + s0 * 4];
      const float4 b1 = *(const float4*)&bufr[lr * 64 + (s0 ^ 1) * 4];
      union { uint4 u; s8v v; } BH, BL;
      {
        const float f0 = b0.x, f1 = b0.y, f2 = b0.z, f3 = b0.w;
        const float f4v = b1.x, f5 = b1.y, f6 = b1.z, f7 = b1.w;
        unsigned u0 = __float_as_uint(f0), u1 = __float_as_uint(f1);
        unsigned u2 = __float_as_uint(f2), u3 = __float_as_uint(f3);
        unsigned u4 = __float_as_uint(f4v), u5 = __float_as_uint(f5);
        unsigned u6 = __float_as_uint(f6), u7 = __float_as_uint(f7);
        BH.u.x = (u0 >> 16) | (u1 & 0xffff0000u);
        BH.u.y = (u2 >> 16) | (u3 & 0xffff0000u);
        BH.u.z = (u4 >> 16) | (u5 & 0xffff0000u);
        BH.u.w = (u6 >> 16) | (u7 & 0xffff0000u);
        const float l0 = f0 - __uint_as_float(u0 & 0xffff0000u);
        const float l1 = f1 - __uint_as_float(u1 & 0xffff0000u);
        const float l2 = f2 - __uint_as_float(u2 & 0xffff0000u);
        const float l3 = f3 - __uint_as_float(u3 & 0xffff0000u);
        const float l4 = f4v - __uint_as_float(u4 & 0xffff0000u);
        const float l5 = f5 - __uint_as_float(u5 & 0xffff0000u);
        const float l6 = f6 - __uint_as_float(u6 & 0xffff0000u);
        const float l7 = f7 - __uint_as_float(u7 & 0xffff0000u);
        BL.u.x = (__float_as_uint(l0) >> 16) | (__float_as_uint(l1) & 0xffff0000u);
        BL.u.y = (__float_as_uint(l2) >> 16) | (__float_as_uint(l3) & 0xffff0000u);
        BL.u.z = (__float_as_uint(l4) >> 16) | (__float_as_uint(l5) & 0xffff0000u);
        BL.u.w = (__float_as_uint(l6) >> 16) | (__float_as_uint(l7) & 0xffff0000u);
      }
      acc = __builtin_amdgcn_mfma_f32_16x16x32_bf16(AH.v, BH.v, acc, 0, 0, 0);
      acc = __builtin_amdgcn_mfma_f32_16x16x32_bf16(AH.v, BL.v, acc, 0, 0, 0);
      acc = __builtin_amdgcn_mfma_f32_16x16x32_bf16(AL.v, BH.v, acc, 0, 0, 0);
    }

    if (ks == 7) {
      const int tile = m >> 3;
      const float y0 = acc[0] + bv.x;
      const float y1 = acc[1] + bv.y;
      const float y2 = acc[2] + bv.z;
      const float y3 = acc[3] + bv.w;
      float4 o;
      if (lk == 0) {
        o.x = 1.0f + sp_f(y0); o.y = 1.0f + sp_f(y1);
        o.z = 1.0f + sp_f(y2); o.w = 1.0f + sp_f(y3);
      } else if (lk == 1) {
        o.x = 0.1f + sp_f(y0); o.y = 0.1f + sp_f(y1);
        o.z = 0.1f + sp_f(y2); o.w = 0.1f + sp_f(y3);
      } else {
        o.x = tanh5_f(y0); o.y = tanh5_f(y1);
        o.z = tanh5_f(y2); o.w = tanh5_f(y3);
      }
      *(float4*)(out + (rowbase + (long)tile * 16 + lr) * T_SIZE + lk * 4) = o;
      acc[0] = 0.f; acc[1] = 0.f; acc[2] = 0.f; acc[3] = 0.f;
    }
  }
}

// ---------- K2a: per-(b, chunk, basis-col) chunk transfer-matrix columns ----------
__global__ void k_scan_chunks(const float* __restrict__ out, float* __restrict__ mats,
                              int nchunks) {
  const int gtid = blockIdx.x * blockDim.x + threadIdx.x;
  const int colslot = gtid & 7;
  const int b = (gtid >> 3) & (T_NBATCH - 1);
  const int chunk = gtid >> 10;
  if (chunk >= nchunks) return;
  if (colslot >= 5) return;

  const int steps = T_NTIME / nchunks;
  const int t0 = chunk * steps;
  const float NEG = -1e30f;
  float f0 = (colslot == 0) ? 0.0f : NEG;
  float f1 = (colslot == 1) ? 0.0f : NEG;
  float f2 = (colslot == 2) ? 0.0f : NEG;
  float f3 = (colslot == 3) ? 0.0f : NEG;
  const float t4 = (colslot == 4) ? 0.0f : NEG;

  const long stride = T_NBATCH * T_SIZE;
  const float* p = out + ((long)t0 * T_NBATCH + b) * T_SIZE + 8;
  float4 mv = *(const float4*)(p);
  float4 st = *(const float4*)(p + 4);
  for (int s = 0; s < steps; ++s) {
    const float* pn = (s + 1 < steps) ? p + stride : p;
    const float4 mvn = *(const float4*)(pn);
    const float4 stn = *(const float4*)(pn + 4);

    float m, ss0, ss1, ss2, ss3;
    m = fmaxf(fmaxf(f1, f2), fmaxf(f3, t4));
    ss0 = m + __logf(__expf(f1 - m) + __expf(f2 - m) + __expf(f3 - m) + __expf(t4 - m));
    m = fmaxf(fmaxf(f0, f2), fmaxf(f3, t4));
    ss1 = m + __logf(__expf(f0 - m) + __expf(f2 - m) + __expf(f3 - m) + __expf(t4 - m));
    m = fmaxf(fmaxf(f0, f1), fmaxf(f3, t4));
    ss2 = m + __logf(__expf(f0 - m) + __expf(f1 - m) + __expf(f3 - m) + __expf(t4 - m));
    m = fmaxf(fmaxf(f0, f1), fmaxf(f2, t4));
    ss3 = m + __logf(__expf(f0 - m) + __expf(f1 - m) + __expf(f2 - m) + __expf(t4 - m));

    const float n0 = lae_f(f0 + st.x, ss0 + mv.x);
    const float n1 = lae_f(f1 + st.y, ss1 + mv.y);
    const float n2 = lae_f(f2 + st.z, ss2 + mv.z);
    const float n3 = lae_f(f3 + st.w, ss3 + mv.w);
    f0 = n0; f1 = n1; f2 = n2; f3 = n3;
    mv = mvn; st = stn; p = pn;
  }
  float* d = mats + ((long)chunk * T_NBATCH + b) * MAT_STRIDE + colslot * 4;
  float4 o; o.x = f0; o.y = f1; o.z = f2; o.w = f3;
  *(float4*)d = o;
}

// ---------- K2b: serial combine of chunk matrices per batch; logZ/T out ----------
__global__ void k_combine(const float* __restrict__ mats, float* __restrict__ logz,
                          int nchunks) {
  const int tid = threadIdx.x;
  const int i = tid & 3;
  const int b = tid >> 2;
  if (b >= T_NBATCH) return;
  float v = 0.0f;

  const float* Tb = mats + (long)b * MAT_STRIDE;
  const long cstride = (long)T_NBATCH * MAT_STRIDE;
  float q0 = Tb[i * 4 + i];
  float q1 = Tb[((i ^ 1) * 4) + i];
  float q2 = Tb[((i ^ 2) * 4) + i];
  float q3 = Tb[((i ^ 3) * 4) + i];
  float q4 = Tb[16 + i];
  for (int c = 0; c < nchunks; ++c) {
    const float* Tn = Tb + cstride;
    float n0 = 0, n1 = 0, n2 = 0, n3 = 0, n4 = 0;
    if (c + 1 < nchunks) {
      n0 = Tn[i * 4 + i];
      n1 = Tn[((i ^ 1) * 4) + i];
      n2 = Tn[((i ^ 2) * 4) + i];
      n3 = Tn[((i ^ 3) * 4) + i];
      n4 = Tn[16 + i];
    }
    const float vx1 = __shfl_xor(v, 1);
    const float vx2 = __shfl_xor(v, 2);
    const float vx3 = __shfl_xor(v, 3);
    const float a0 = q0 + v;
    const float a1 = q1 + vx1;
    const float a2 = q2 + vx2;
    const float a3 = q3 + vx3;
    const float a4 = q4;
    float m = fmaxf(fmaxf(a0, a1), fmaxf(fmaxf(a2, a3), a4));
    v = m + __logf(__expf(a0 - m) + __expf(a1 - m) + __expf(a2 - m) +
                   __expf(a3 - m) + __expf(a4 - m));
    q0 = n0; q1 = n1; q2 = n2; q3 = n3; q4 = n4;
    Tb = Tn;
  }
  float m1 = fmaxf(v, __shfl_xor(v, 1));
  m1 = fmaxf(m1, __shfl_xor(m1, 2));
  float e = __expf(v - m1);
  e += __shfl_xor(e, 1);
  e += __shfl_xor(e, 2);
  const float lz = m1 + __logf(e);
  if (i == 0) logz[b] = lz * (1.0f / (float)T_NTIME);
}

// ---------- K3: out[t][b][8..15] -= logZ[b]/T ----------
__global__ void k_sub(float* __restrict__ out, const float* __restrict__ logz) {
  const long n = (long)blockIdx.x * blockDim.x + threadIdx.x;
  if (n >= (long)T_NROWS * 2) return;
  const long tb = n >> 1;
  const int b = (int)(tb & (T_NBATCH - 1));
  const float lz = logz[b];
  float4* p = (float4*)(out + tb * T_SIZE + 8 + (n & 1) * 4);
  float4 v = *p;
  v.x -= lz; v.y -= lz; v.z -= lz; v.w -= lz;
  *p = v;
}

extern "C" void kernel_launch(void* const* d_in, const int* in_sizes, int n_in,
                              void* d_out, int out_size, void* d_ws, size_t ws_size,
                              hipStream_t stream) {
  const float* x    = (const float*)d_in[0];
  const float* W    = (const float*)d_in[1];
  const float* bias = (const float*)d_in[2];
  float* out = (float*)d_out;
  float* ws  = (float*)d_ws;

  int C = 64;
  while (C > 1 && (size_t)((long)C * T_NBATCH * MAT_STRIDE + T_NBATCH) * 4 > ws_size) C >>= 1;
  float* mats = ws;
  float* logz = ws + (long)C * T_NBATCH * MAT_STRIDE;

  k1_gld<<<512, 256, 0, stream>>>(x, W, bias, out);

  const int thr2 = C * T_NBATCH * 8;
  k_scan_chunks<<<thr2 / 256, 256, 0, stream>>>(out, mats, C);
  k_combine<<<1, 512, 0, stream>>>(mats, logz, C);
  k_sub<<<(T_NROWS * 2) / 256, 256, 0, stream>>>(out, logz);
}